// Round 4
// baseline (323.406 us; speedup 1.0000x reference)
//
#include <hip/hip_runtime.h>
#include <hip/hip_fp16.h>

typedef _Float16 half8 __attribute__((ext_vector_type(8)));
typedef _Float16 half4 __attribute__((ext_vector_type(4)));
typedef float    floatx4 __attribute__((ext_vector_type(4)));

#define MFMA16(a, b, c) __builtin_amdgcn_mfma_f32_16x16x32_f16((a), (b), (c), 0, 0, 0)

constexpr int T_ = 2048;
constexpr int D_ = 1024;
constexpr int NB = 4;
constexpr int BC = 128;            // kv super-tile

__device__ __forceinline__ half8 cvt8(floatx4 a, floatx4 b) {
  half8 h;
  h[0] = (_Float16)a[0]; h[1] = (_Float16)a[1]; h[2] = (_Float16)a[2]; h[3] = (_Float16)a[3];
  h[4] = (_Float16)b[0]; h[5] = (_Float16)b[1]; h[6] = (_Float16)b[2]; h[7] = (_Float16)b[3];
  return h;
}

// ---- prep: cast V->f16 (Vh) and build transposed VhT[D][T] ----
template <int MODE>
__global__ __launch_bounds__(256) void prep(const float* __restrict__ V,
                                            _Float16* __restrict__ VhT,
                                            _Float16* __restrict__ Vh) {
  __shared__ _Float16 tile[64][65];
  const int bid = blockIdx.x;
  const int b = bid & 3;
  const int tt = (bid >> 2) & 31;
  const int dd = bid >> 7;
  const float* Vb = V + ((size_t)b * T_ + tt * 64) * D_ + dd * 64;
#pragma unroll
  for (int k = 0; k < 16; ++k) {
    const int e = k * 256 + threadIdx.x;
    const int r = e >> 6, c = e & 63;
    const _Float16 h = (_Float16)Vb[(size_t)r * D_ + c];
    tile[r][c] = h;
    if (MODE == 2) Vh[((size_t)b * T_ + tt * 64 + r) * D_ + dd * 64 + c] = h;
  }
  __syncthreads();
#pragma unroll
  for (int k = 0; k < 16; ++k) {
    const int e = k * 256 + threadIdx.x;
    const int dr = e >> 6, tc = e & 63;
    VhT[((size_t)b * D_ + dd * 64 + dr) * T_ + tt * 64 + tc] = tile[tc][dr];
  }
}

template <int MODE>
__device__ __forceinline__ half8 loadA(const _Float16* __restrict__ Vhb,
                                       const float* __restrict__ Vb, int row, int col) {
  if (MODE == 2) return *(const half8*)(Vhb + (size_t)row * D_ + col);
  const float* p = Vb + (size_t)row * D_ + col;
  return cvt8(*(const floatx4*)p, *(const floatx4*)(p + 4));
}

template <int MODE>
__device__ __forceinline__ half8 loadB(const _Float16* __restrict__ VhTb,
                                       const float* __restrict__ Vb, int dim, int kv) {
  if (MODE >= 1) return *(const half8*)(VhTb + (size_t)dim * T_ + kv);
  half8 h;
#pragma unroll
  for (int j = 0; j < 8; ++j) h[j] = (_Float16)Vb[(size_t)(kv + j) * D_ + dim];
  return h;
}

// ---- causal flash attention, K=V, Br=16, Bc=128, kv-split across 8 waves ----
template <int MODE>
__global__ __launch_bounds__(512, 2) void attn(const float* __restrict__ Qg,
                                               const float* __restrict__ Vg,
                                               const _Float16* __restrict__ VhTg,
                                               const _Float16* __restrict__ Vhg,
                                               float* __restrict__ Og) {
  __shared__ char QL[16 * 2048];   // Q f16 [16 q][1024 d], XOR-swizzled
  __shared__ char PL[16 * 256];    // P f16 [16 q][128 kv], XOR-swizzled
  __shared__ float WM[8][16];      // per-wave row max
  __shared__ float WS[8][16];      // per-wave row sum
  __shared__ float Msh[16], Lsh[16], ALsh[16];

  const int tid = threadIdx.x;
  const int w = tid >> 6, l = tid & 63, l15 = l & 15, hi = l >> 4;
  const int koff = hi * 8;
  const unsigned swz = (unsigned)((l15 & 7) << 4);

  // static balanced schedule; b and b+256 co-reside on a CU (round-robin
  // dispatch) -> long strip pairs with short strip; batch->XCD affinity kept.
  const int b = (int)blockIdx.x;
  const int batch = b & 3;
  const int j = (b >> 2) & 63;
  const int s = (b < 256) ? (127 - j) : j;
  const int qbase = s * 16;
  const int ntiles = (qbase + 16 + BC - 1) / BC;

  const float* Qb = Qg + (size_t)batch * T_ * D_;
  const float* Vb = Vg + (size_t)batch * T_ * D_;
  const _Float16* VhTb = (MODE >= 1) ? VhTg + (size_t)batch * T_ * D_ : (const _Float16*)nullptr;
  const _Float16* Vhb  = (MODE == 2) ? Vhg  + (size_t)batch * T_ * D_ : (const _Float16*)nullptr;

  // ---- stage Q (f32 -> f16) into swizzled LDS; init running m/l ----
  {
    const int row = tid >> 5;                 // q-row 0..15
    const int c0 = (tid & 31) * 8;            // 32 lanes * 8 cols, coalesced
#pragma unroll
    for (int i = 0; i < 4; ++i) {
      const int col = c0 + i * 256;
      const float* p = Qb + (size_t)(qbase + row) * D_ + col;
      half8 h = cvt8(*(const floatx4*)p, *(const floatx4*)(p + 4));
      const unsigned byte = (unsigned)(row * 2048) +
                            (((unsigned)(col * 2)) ^ (unsigned)((row & 7) << 4));
      *(half8*)(QL + byte) = h;
    }
    if (tid < 16) { Msh[tid] = -1e30f; Lsh[tid] = 0.f; }
  }
  __syncthreads();

  floatx4 accO[8];
#pragma unroll
  for (int f = 0; f < 8; ++f) accO[f] = (floatx4){0.f, 0.f, 0.f, 0.f};

  half8 bva[8], bvb[8];

  for (int t = 0; t < ntiles; ++t) {
    const int kv0 = t * BC;
    const int kw0 = kv0 + 16 * w;            // this wave's 16 kv rows
    const float Mold = Msh[l15];             // stable: last write was pre-barB(t-1)

    // ---- QK: S^T[16 kv x 16 q], full D reduction, 4 interleaved accumulators ----
    floatx4 sA = {0.f,0.f,0.f,0.f}, sB = sA, sC = sA, sD = sA;
    const _Float16* arow = (MODE == 2) ? Vhb + (size_t)(kw0 + l15) * D_ + koff : nullptr;
#pragma unroll
    for (int c = 0; c < 32; c += 4) {
      half8 a0, a1, a2, a3;
      if (MODE == 2) {
        a0 = *(const half8*)(arow + (c + 0) * 32);
        a1 = *(const half8*)(arow + (c + 1) * 32);
        a2 = *(const half8*)(arow + (c + 2) * 32);
        a3 = *(const half8*)(arow + (c + 3) * 32);
      } else {
        a0 = loadA<MODE>(Vhb, Vb, kw0 + l15, (c + 0) * 32 + koff);
        a1 = loadA<MODE>(Vhb, Vb, kw0 + l15, (c + 1) * 32 + koff);
        a2 = loadA<MODE>(Vhb, Vb, kw0 + l15, (c + 2) * 32 + koff);
        a3 = loadA<MODE>(Vhb, Vb, kw0 + l15, (c + 3) * 32 + koff);
      }
      half8 q0 = *(const half8*)(QL + (unsigned)(l15 * 2048) + (((unsigned)((c + 0) * 64 + hi * 16)) ^ swz));
      half8 q1 = *(const half8*)(QL + (unsigned)(l15 * 2048) + (((unsigned)((c + 1) * 64 + hi * 16)) ^ swz));
      half8 q2 = *(const half8*)(QL + (unsigned)(l15 * 2048) + (((unsigned)((c + 2) * 64 + hi * 16)) ^ swz));
      half8 q3 = *(const half8*)(QL + (unsigned)(l15 * 2048) + (((unsigned)((c + 3) * 64 + hi * 16)) ^ swz));
      sA = MFMA16(a0, q0, sA);
      sB = MFMA16(a1, q1, sB);
      sC = MFMA16(a2, q2, sC);
      sD = MFMA16(a3, q3, sD);
    }

    // issue PV c=0 loads now: in flight across softmax + barriers
#pragma unroll
    for (int f = 0; f < 8; ++f)
      bva[f] = loadB<MODE>(VhTb, Vb, w * 128 + f * 16 + l15, kv0 + koff);

    floatx4 sv = (sA + sB) + (sC + sD);      // S rows kw0+4hi+r, col q=l15
#pragma unroll
    for (int r = 0; r < 4; ++r)
      if (kw0 + 4 * hi + r > qbase + l15) sv[r] = -1e30f;   // causal mask

    float pm = fmaxf(fmaxf(sv[0], sv[1]), fmaxf(sv[2], sv[3]));
    pm = fmaxf(pm, __shfl_xor(pm, 16));
    pm = fmaxf(pm, __shfl_xor(pm, 32));      // max over wave's 16 kv, per q=l15
    if (l < 16) WM[w][l] = pm;
    __syncthreads();                          // bar A

    float mnew = Mold;
#pragma unroll
    for (int ww = 0; ww < 8; ++ww) mnew = fmaxf(mnew, WM[ww][l15]);

    float ps = 0.f; half4 ph;
#pragma unroll
    for (int r = 0; r < 4; ++r) {
      const float p = __expf(sv[r] - mnew);
      ps += p; ph[r] = (_Float16)p;
    }
    ps += __shfl_xor(ps, 16);
    ps += __shfl_xor(ps, 32);                 // sum over wave's 16 kv
    {
      const unsigned pb = (unsigned)(l15 * 256) +
                          (((unsigned)((16 * w + 4 * hi) * 2)) ^ swz);
      *(half4*)(PL + pb) = ph;                // P[q=l15][kv=16w+4hi..+3]
    }
    if (l < 16) WS[w][l] = ps;
    if (w == 0 && l < 16) {                   // alpha + M update (L after barB)
      ALsh[l] = __expf(Mold - mnew);
      Msh[l] = mnew;
    }
    __syncthreads();                          // bar B

    if (w == 0 && l < 16) {
      float acc = Lsh[l] * ALsh[l];
#pragma unroll
      for (int ww = 0; ww < 8; ++ww) acc += WS[ww][l];
      Lsh[l] = acc;
    }

    // rescale accO rows (q = 4hi+r)
    float ar[4];
#pragma unroll
    for (int r = 0; r < 4; ++r) ar[r] = ALsh[4 * hi + r];
#pragma unroll
    for (int f = 0; f < 8; ++f)
#pragma unroll
      for (int r = 0; r < 4; ++r) accO[f][r] *= ar[r];

    // ---- PV: O[16 q][128-d slice] += P[16][128] * V^T, pipelined over c ----
#pragma unroll
    for (int f = 0; f < 8; ++f)
      bvb[f] = loadB<MODE>(VhTb, Vb, w * 128 + f * 16 + l15, kv0 + 32 + koff);
    {
      const unsigned pb = (unsigned)(l15 * 256) + (((unsigned)(hi * 16)) ^ swz);
      const half8 pa = *(const half8*)(PL + pb);
#pragma unroll
      for (int f = 0; f < 8; ++f) accO[f] = MFMA16(pa, bva[f], accO[f]);
    }
#pragma unroll
    for (int f = 0; f < 8; ++f)
      bva[f] = loadB<MODE>(VhTb, Vb, w * 128 + f * 16 + l15, kv0 + 64 + koff);
    {
      const unsigned pb = (unsigned)(l15 * 256) + (((unsigned)(64 + hi * 16)) ^ swz);
      const half8 pa = *(const half8*)(PL + pb);
#pragma unroll
      for (int f = 0; f < 8; ++f) accO[f] = MFMA16(pa, bvb[f], accO[f]);
    }
#pragma unroll
    for (int f = 0; f < 8; ++f)
      bvb[f] = loadB<MODE>(VhTb, Vb, w * 128 + f * 16 + l15, kv0 + 96 + koff);
    {
      const unsigned pb = (unsigned)(l15 * 256) + (((unsigned)(128 + hi * 16)) ^ swz);
      const half8 pa = *(const half8*)(PL + pb);
#pragma unroll
      for (int f = 0; f < 8; ++f) accO[f] = MFMA16(pa, bva[f], accO[f]);
    }
    {
      const unsigned pb = (unsigned)(l15 * 256) + (((unsigned)(192 + hi * 16)) ^ swz);
      const half8 pa = *(const half8*)(PL + pb);
#pragma unroll
      for (int f = 0; f < 8; ++f) accO[f] = MFMA16(pa, bvb[f], accO[f]);
    }
    // next tile's WM/WS/PL writes are gated by barA(t+1), which needs all
    // waves done with this tile's PV -> no extra barrier here.
  }

  __syncthreads();                            // Lsh final visible
  float inv[4];
#pragma unroll
  for (int r = 0; r < 4; ++r) inv[r] = 1.0f / Lsh[4 * hi + r];
  float* Ob = Og + ((size_t)batch * T_ + qbase) * D_;
#pragma unroll
  for (int f = 0; f < 8; ++f) {
    const int dim = w * 128 + f * 16 + l15;
#pragma unroll
    for (int r = 0; r < 4; ++r)
      Ob[(size_t)(4 * hi + r) * D_ + dim] = accO[f][r] * inv[r];
  }
}

extern "C" void kernel_launch(void* const* d_in, const int* in_sizes, int n_in,
                              void* d_out, int out_size, void* d_ws, size_t ws_size,
                              hipStream_t stream) {
  const float* q = (const float*)d_in[0];
  const float* v = (const float*)d_in[1];
  float* out = (float*)d_out;
  const size_t NE = (size_t)NB * T_ * D_;
  const size_t HB = NE * sizeof(_Float16);   // 16 MiB

  if (ws_size >= 2 * HB) {
    _Float16* vt = (_Float16*)d_ws;
    _Float16* vh = (_Float16*)((char*)d_ws + HB);
    prep<2><<<dim3(2048), dim3(256), 0, stream>>>(v, vt, vh);
    attn<2><<<dim3(512), dim3(512), 0, stream>>>(q, v, vt, vh, out);
  } else if (ws_size >= HB) {
    _Float16* vt = (_Float16*)d_ws;
    prep<1><<<dim3(2048), dim3(256), 0, stream>>>(v, vt, nullptr);
    attn<1><<<dim3(512), dim3(512), 0, stream>>>(q, v, vt, nullptr, out);
  } else {
    attn<0><<<dim3(512), dim3(512), 0, stream>>>(q, v, nullptr, nullptr, out);
  }
}